// Round 8
// baseline (596.581 us; speedup 1.0000x reference)
//
#include <hip/hip_runtime.h>
#include <math.h>

#define B_    2048
#define N_    36
#define EMB_  1024
#define SIMD_ 16
#define HID_  32
#define K_    8

// Split design (H1/H2 test):
//  Kernel A (sim_stream_kernel): pure streaming cosine sims. No LDS, no
//    barriers, no weight prep. Each wave owns 9 contiguous rows; 3-deep
//    rotating register buffers, hand-unrolled 9 steps with NO buffer copies:
//    each COMP consumes the oldest 8 loads while 16 newer loads stay in
//    flight (compiler emits counted s_waitcnt vmcnt, never a full drain).
//    Sims go to workspace ws[(b*36+i)*16+d] (4.7 MB, L2/L3-resident for B).
//  Kernel B (mlp_kernel): the previously verified phase-0 weight fold +
//    cell-parallel 2A/2B/2C MLP, sourcing sims from ws. ~5-10 us.
//  Fallback: verified round-6 fused kernel if ws_size < 4.7 MB.
// NOTE: the Gaussian-kernel graph weights row-normalize to sum S/(S+1e-8) ~= 1
// (error <= ~1.2e-8, far below the 1.55e-3 absmax threshold), and the node
// features are j-independent, so the whole pairwise-distance pipeline folds
// to identity. gk_mean/gk_prec are provably irrelevant at this tolerance.

// 16-lane (DPP-row) sum reduction stage: x += dpp(x, CTRL)
template<int CTRL>
__device__ __forceinline__ float dpp_add(float x) {
    int t = __builtin_amdgcn_update_dpp(0, __builtin_bit_cast(int, x),
                                        CTRL, 0xf, 0xf, false);
    return x + __builtin_bit_cast(float, t);
}
// full 16-lane sum: quad xor1, quad xor2, then ror:4 + ror:8 sweep the quads.
__device__ __forceinline__ float row16_sum(float x) {
    x = dpp_add<0xB1>(x);    // quad_perm [1,0,3,2]  (xor 1)
    x = dpp_add<0x4E>(x);    // quad_perm [2,3,0,1]  (xor 2)
    x = dpp_add<0x124>(x);   // row_ror:4
    x = dpp_add<0x128>(x);   // row_ror:8
    return x;
}

// ---------------- Kernel A: streaming sims ----------------
__global__ __launch_bounds__(256) void sim_stream_kernel(
    const float* __restrict__ inp1, const float* __restrict__ inp2,
    float* __restrict__ ws)
{
    const int tid  = threadIdx.x;
    const int b    = blockIdx.x;
    const int wave = tid >> 6;
    const int lane = tid & 63;
    const int g    = lane >> 4;              // 16-lane group id (DPP row)
    const int row0 = wave * 9;               // this wave owns rows row0..row0+8

    const float4* p1 = reinterpret_cast<const float4*>(inp1 + ((size_t)b * N_ + row0) * EMB_) + lane;
    const float4* p2 = reinterpret_cast<const float4*>(inp2 + ((size_t)b * N_ + row0) * EMB_) + lane;
    float* wsout = ws + ((size_t)b * N_ + row0) * SIMD_;

    float4 q0[4], c0[4], q1[4], c1[4], q2[4], c2[4];   // 3 rotating row buffers

    // instr u reads float4 index r*256 + 64u + lane: one 1KB coalesced
    // transaction per instruction; lane's partial belongs to sim block 4u+g.
#define LOADR(Q, C, r)                                                         \
    { _Pragma("unroll") for (int u = 0; u < 4; ++u) {                          \
        Q[u] = p1[(r) * 256 + 64 * u]; C[u] = p2[(r) * 256 + 64 * u]; } }
#define COMPR(Q, C, r)                                                         \
    { _Pragma("unroll") for (int u = 0; u < 4; ++u) {                          \
        float4 q = Q[u], c = C[u];                                             \
        float qq = q.x*q.x + q.y*q.y + q.z*q.z + q.w*q.w;                      \
        float cc = c.x*c.x + c.y*c.y + c.z*c.z + c.w*c.w;                      \
        float qc = q.x*c.x + q.y*c.y + q.z*c.z + q.w*c.w;                      \
        qq = row16_sum(qq); cc = row16_sum(cc); qc = row16_sum(qc);            \
        if ((lane & 15) == 0)                                                  \
            wsout[(r) * SIMD_ + 4 * u + g] = qc * rsqrtf(qq * cc); } }

    LOADR(q0, c0, 0) LOADR(q1, c1, 1) LOADR(q2, c2, 2)   // prologue: 3 rows in flight
    COMPR(q0, c0, 0) LOADR(q0, c0, 3)
    COMPR(q1, c1, 1) LOADR(q1, c1, 4)
    COMPR(q2, c2, 2) LOADR(q2, c2, 5)
    COMPR(q0, c0, 3) LOADR(q0, c0, 6)
    COMPR(q1, c1, 4) LOADR(q1, c1, 7)
    COMPR(q2, c2, 5) LOADR(q2, c2, 8)
    COMPR(q0, c0, 6)
    COMPR(q1, c1, 7)
    COMPR(q2, c2, 8)
#undef LOADR
#undef COMPR
}

// ---------------- Kernel B: weight fold + MLP ----------------
__global__ __launch_bounds__(256) void mlp_kernel(
    const float* __restrict__ ws,
    const float* __restrict__ gcn_w,
    const float* __restrict__ out1_v, const float* __restrict__ out1_g,
    const float* __restrict__ out1_b,
    const float* __restrict__ out2_v, const float* __restrict__ out2_g,
    const float* __restrict__ out2_b,
    float* __restrict__ out)
{
    __shared__ float sSim[N_][SIMD_ + 1];
    __shared__ float sWsum[SIMD_][HID_];
    __shared__ float sW1[HID_][HID_ + 1];
    __shared__ float sB1[HID_];
    __shared__ float sW2[HID_];
    __shared__ float sG[N_][HID_ + 1];
    __shared__ float sT[N_][HID_ + 1];

    const int tid = threadIdx.x;
    const int b   = blockIdx.x;

    // load sims (L2/L3-resident: kernel A just wrote them)
    const float* wsin = ws + (size_t)b * N_ * SIMD_;
    for (int idx = tid; idx < N_ * SIMD_; idx += 256)
        sSim[idx / SIMD_][idx % SIMD_] = wsin[idx];

    // fold weights (reads hit L2 after first blocks)
    for (int idx = tid; idx < SIMD_ * HID_; idx += 256) {
        float s = 0.f;
        #pragma unroll
        for (int k = 0; k < K_; ++k) s += gcn_w[k * SIMD_ * HID_ + idx];
        sWsum[idx / HID_][idx % HID_] = s;
    }
    if (tid < HID_) {
        float nrm = 0.f;
        #pragma unroll
        for (int h = 0; h < HID_; ++h) { float v = out1_v[tid * HID_ + h]; nrm += v * v; }
        float sc = out1_g[tid] / (sqrtf(nrm) + 1e-12f);
        #pragma unroll
        for (int h = 0; h < HID_; ++h) sW1[tid][h] = out1_v[tid * HID_ + h] * sc;
        sB1[tid] = out1_b[tid];
    } else if (tid >= 64 && tid < 64 + HID_) {
        int h = tid - 64;
        float nrm = 0.f;
        #pragma unroll
        for (int j = 0; j < HID_; ++j) { float v = out2_v[j]; nrm += v * v; }
        sW2[h] = out2_g[0] * out2_v[h] / (sqrtf(nrm) + 1e-12f);
    }
    __syncthreads();

    // 2A: g1[i][h] = sum_d sim[i][d] * Wsum[d][h]
    for (int c = tid; c < N_ * HID_; c += 256) {
        const int i = c >> 5;
        const int h = c & (HID_ - 1);
        float a = 0.f;
        #pragma unroll
        for (int d = 0; d < SIMD_; ++d) a += sSim[i][d] * sWsum[d][h];
        sG[i][h] = a;
    }
    __syncthreads();

    // 2B: t[i][h2] = tanh(b1[h2] + W1[h2,:].g1[i,:])
    for (int c = tid; c < N_ * HID_; c += 256) {
        const int i  = c >> 5;
        const int h2 = c & (HID_ - 1);
        float a = sB1[h2];
        #pragma unroll
        for (int h = 0; h < HID_; ++h) a += sW1[h2][h] * sG[i][h];
        sT[i][h2] = tanhf(a);
    }
    __syncthreads();

    // 2C: row scores + mean (wave 0)
    if (tid < 64) {
        float sv = 0.f;
        if (tid < N_) {
            float acc = out2_b[0];
            #pragma unroll
            for (int h = 0; h < HID_; ++h) acc += sW2[h] * sT[tid][h];
            sv = acc;
        }
        #pragma unroll
        for (int m = 1; m < 64; m <<= 1) sv += __shfl_xor(sv, m, 64);
        if (tid == 0) out[b] = sv * (1.f / (float)N_);
    }
}

// ---------------- Fallback: verified round-6 fused kernel ----------------
__global__ __launch_bounds__(256) void simgsmn_fused_kernel(
    const float* __restrict__ inp1, const float* __restrict__ inp2,
    const float* __restrict__ gcn_w,
    const float* __restrict__ out1_v, const float* __restrict__ out1_g,
    const float* __restrict__ out1_b,
    const float* __restrict__ out2_v, const float* __restrict__ out2_g,
    const float* __restrict__ out2_b,
    float* __restrict__ out)
{
    __shared__ float sSim[N_][SIMD_ + 1];
    __shared__ float sWsum[SIMD_][HID_];
    __shared__ float sW1[HID_][HID_ + 1];
    __shared__ float sB1[HID_];
    __shared__ float sW2[HID_];
    __shared__ float sG[N_][HID_ + 1];
    __shared__ float sT[N_][HID_ + 1];

    const int tid = threadIdx.x;
    const int b   = blockIdx.x;

    for (int idx = tid; idx < SIMD_ * HID_; idx += 256) {
        float s = 0.f;
        #pragma unroll
        for (int k = 0; k < K_; ++k) s += gcn_w[k * SIMD_ * HID_ + idx];
        sWsum[idx / HID_][idx % HID_] = s;
    }
    if (tid < HID_) {
        float nrm = 0.f;
        #pragma unroll
        for (int h = 0; h < HID_; ++h) { float v = out1_v[tid * HID_ + h]; nrm += v * v; }
        float sc = out1_g[tid] / (sqrtf(nrm) + 1e-12f);
        #pragma unroll
        for (int h = 0; h < HID_; ++h) sW1[tid][h] = out1_v[tid * HID_ + h] * sc;
        sB1[tid] = out1_b[tid];
    } else if (tid >= 64 && tid < 64 + HID_) {
        int h = tid - 64;
        float nrm = 0.f;
        #pragma unroll
        for (int j = 0; j < HID_; ++j) { float v = out2_v[j]; nrm += v * v; }
        sW2[h] = out2_g[0] * out2_v[h] / (sqrtf(nrm) + 1e-12f);
    }
    __syncthreads();

    const int wave = tid >> 6;
    const int lane = tid & 63;
    const int g    = lane >> 4;

    const float4* basep1 = reinterpret_cast<const float4*>(inp1 + (size_t)b * N_ * EMB_) + lane;
    const float4* basep2 = reinterpret_cast<const float4*>(inp2 + (size_t)b * N_ * EMB_) + lane;

    float4 qa[4], ca[4], qb[4], cb[4];
    {
        const float4* p1 = basep1 + wave * 256;
        const float4* p2 = basep2 + wave * 256;
        #pragma unroll
        for (int u = 0; u < 4; ++u) { qa[u] = p1[64 * u]; ca[u] = p2[64 * u]; }
    }
    #pragma unroll
    for (int it = 0; it < 9; ++it) {
        const int i = wave + 4 * it;
        if (it < 8) {
            const float4* p1 = basep1 + (i + 4) * 256;
            const float4* p2 = basep2 + (i + 4) * 256;
            #pragma unroll
            for (int u = 0; u < 4; ++u) { qb[u] = p1[64 * u]; cb[u] = p2[64 * u]; }
        }
        #pragma unroll
        for (int u = 0; u < 4; ++u) {
            float4 q = qa[u], c = ca[u];
            float qq = q.x * q.x + q.y * q.y + q.z * q.z + q.w * q.w;
            float cc = c.x * c.x + c.y * c.y + c.z * c.z + c.w * c.w;
            float qc = q.x * c.x + q.y * c.y + q.z * c.z + q.w * c.w;
            qq = row16_sum(qq);
            cc = row16_sum(cc);
            qc = row16_sum(qc);
            if ((lane & 15) == 0) sSim[i][4 * u + g] = qc * rsqrtf(qq * cc);
        }
        #pragma unroll
        for (int u = 0; u < 4; ++u) { qa[u] = qb[u]; ca[u] = cb[u]; }
    }
    __syncthreads();

    for (int c = tid; c < N_ * HID_; c += 256) {
        const int i = c >> 5;
        const int h = c & (HID_ - 1);
        float a = 0.f;
        #pragma unroll
        for (int d = 0; d < SIMD_; ++d) a += sSim[i][d] * sWsum[d][h];
        sG[i][h] = a;
    }
    __syncthreads();

    for (int c = tid; c < N_ * HID_; c += 256) {
        const int i  = c >> 5;
        const int h2 = c & (HID_ - 1);
        float a = sB1[h2];
        #pragma unroll
        for (int h = 0; h < HID_; ++h) a += sW1[h2][h] * sG[i][h];
        sT[i][h2] = tanhf(a);
    }
    __syncthreads();

    if (tid < 64) {
        float sv = 0.f;
        if (tid < N_) {
            float acc = out2_b[0];
            #pragma unroll
            for (int h = 0; h < HID_; ++h) acc += sW2[h] * sT[tid][h];
            sv = acc;
        }
        #pragma unroll
        for (int m = 1; m < 64; m <<= 1) sv += __shfl_xor(sv, m, 64);
        if (tid == 0) out[b] = sv * (1.f / (float)N_);
    }
}

extern "C" void kernel_launch(void* const* d_in, const int* in_sizes, int n_in,
                              void* d_out, int out_size, void* d_ws, size_t ws_size,
                              hipStream_t stream) {
    const float* inp1   = (const float*)d_in[0];
    const float* inp2   = (const float*)d_in[1];
    // d_in[2] = gk_mean, d_in[3] = gk_prec: provably irrelevant (see kernel note)
    const float* gcn_w  = (const float*)d_in[4];
    const float* out1_v = (const float*)d_in[5];
    const float* out1_g = (const float*)d_in[6];
    const float* out1_b = (const float*)d_in[7];
    const float* out2_v = (const float*)d_in[8];
    const float* out2_g = (const float*)d_in[9];
    const float* out2_b = (const float*)d_in[10];
    float* out = (float*)d_out;

    const size_t ws_need = (size_t)B_ * N_ * SIMD_ * sizeof(float);  // 4.7 MB
    if (d_ws != nullptr && ws_size >= ws_need) {
        float* ws = (float*)d_ws;
        sim_stream_kernel<<<B_, 256, 0, stream>>>(inp1, inp2, ws);
        mlp_kernel<<<B_, 256, 0, stream>>>(ws, gcn_w,
                                           out1_v, out1_g, out1_b,
                                           out2_v, out2_g, out2_b, out);
    } else {
        simgsmn_fused_kernel<<<B_, 256, 0, stream>>>(inp1, inp2, gcn_w,
                                                     out1_v, out1_g, out1_b,
                                                     out2_v, out2_g, out2_b, out);
    }
}